// Round 6
// baseline (307.565 us; speedup 1.0000x reference)
//
#include <hip/hip_runtime.h>

// CrossAttentionGAT — algebraically collapsed; ENTIRE pipeline fused into one
// persistent kernel with device-scope grid barriers (launch-overhead was the
// bottleneck: ~10 dispatches x ~10-15us serial launch/drain).
//
// mean(cross1) = mean(emb2) @ Wl + bl   (softmax col-sums == 1)
// mean(cross2) = mean(emb1) @ Wl + bl   (softmax row-sums == 1)
// mean(emb)    = (1/N) * sum_k g[head,k] * W[k, head*C+c] + b
//   g[head,k]  = sum_n w[n,head] x[n,k],  w[n,head] = sum_{e: src=n} alpha_e[head]
//
// Phases: P0 bin(+u) | P1 a | P2 den | P3 wacc | P4 gred-part | P5 g-reduce
//        | P6 memb | P7 out.  256 blocks x 512 thr; 1 block/CU guaranteed
// schedulable (capacity 4 blocks/CU >> 1), so spin barriers cannot deadlock.

#define NN 8192
#define EE 262144
#define NEG 0.2f
#define BKT 128
#define RNG 64            // nodes per bucket
#define CAP 2560          // bucket capacity: mean 2048 + >11 sigma
#define CHK 2048          // edges per bin unit
#define GRID 256

// ---------------- ws layout (4-byte units) ----------------
#define U_BAR  0                       // 1 int (zeroed)
#define U_CNT  1                       // 4*BKT ints (zeroed)
#define U_ZEND (U_CNT + 4*BKT)
#define U_U    1024                    // 2*2048 floats
#define U_ASRC (U_U + 4096)            // 2*NN*8
#define U_ADST (U_ASRC + 131072)       // 2*NN*8
#define U_PR   (U_ADST + 131072)       // 2*NN*8 float2 = 262144 units
#define U_WACC (U_PR + 262144)         // 2*NN*8
#define U_GP   (U_WACC + 131072)       // 256*1024 partials
#define U_GG   (U_GP + 262144)         // 2*1024
#define U_MEMB (U_GG + 2048)           // 2*1024
#define U_BIND (U_MEMB + 2048)         // 2*BKT*CAP
#define U_BINS (U_BIND + 2*BKT*CAP)    // 2*BKT*CAP
#define ZERO_BYTES ((size_t)U_ZEND * 4)

__device__ __forceinline__ void gbar(int* bar, int target) {
  __syncthreads();                     // drains each wave's vmcnt: stores in L2
  if (threadIdx.x == 0) {
    __threadfence();                   // agent release: L2 writeback (cross-XCD)
    atomicAdd(bar, 1);
    while (atomicAdd(bar, 0) < target) {
      __builtin_amdgcn_s_sleep(2);
    }
    __threadfence();                   // agent acquire: invalidate stale lines
  }
  __syncthreads();
}

__global__ __launch_bounds__(512, 2) void k_mega(
    const float* __restrict__ x1, const int* __restrict__ ei1,
    const float* __restrict__ W1, const float* __restrict__ as1,
    const float* __restrict__ ad1, const float* __restrict__ b1,
    const float* __restrict__ x2, const int* __restrict__ ei2,
    const float* __restrict__ W2, const float* __restrict__ as2,
    const float* __restrict__ ad2, const float* __restrict__ b2,
    const float* __restrict__ Wl, const float* __restrict__ bl,
    float* __restrict__ out, int* __restrict__ ws_i, float* __restrict__ ws_f) {
  int* bar   = ws_i + U_BAR;
  int* cnt   = ws_i + U_CNT;
  float* uu  = ws_f + U_U;
  float* asrc = ws_f + U_ASRC;
  float* adst = ws_f + U_ADST;
  float* pr   = ws_f + U_PR;
  float* wacc = ws_f + U_WACC;
  float* gpart = ws_f + U_GP;
  float* gg   = ws_f + U_GG;
  float* memb = ws_f + U_MEMB;
  int* binD  = ws_i + U_BIND;
  int* binS  = ws_i + U_BINS;

  __shared__ union {
    struct {
      int hD[BKT], hS[BKT], scD[BKT], scS[BKT];
      int cD[BKT], cS[BKT], bD[BKT], bS[BKT];
      int ldsD[CHK], ldsS[CHK];
      unsigned char kbAD[CHK], kbAS[CHK];
    } bin;                                   // 24.5 KB
    struct { float xs[64][129]; float us[16][128]; } a;   // 41 KB
    struct { float den[RNG * 8]; float adsts[RNG * 8]; } dr;  // 4 KB
    struct { float wv[RNG * 8]; float asrcs[RNG * 8]; } wr;   // 4 KB
    float red[512];
  } sm;

  int t = threadIdx.x;

  // ---------- P0: bin edges (all blocks) + u (blocks 0..31) ----------
  {
    int unit = blockIdx.x, g = unit >> 7, chunk = unit & 127;
    const int* ei = g ? ei2 : ei1;
    if (t < BKT) { sm.bin.hD[t] = 0; sm.bin.cD[t] = 0; }
    else if (t < 2 * BKT) { int i = t - BKT; sm.bin.hS[i] = 0; sm.bin.cS[i] = 0; }
    __syncthreads();
    int e0 = chunk * CHK;
    int sv[4], dv[4];
#pragma unroll
    for (int k = 0; k < 4; ++k) {
      sv[k] = ei[e0 + t + k * 512];
      dv[k] = ei[EE + e0 + t + k * 512];
      atomicAdd(&sm.bin.hD[dv[k] >> 6], 1);
      atomicAdd(&sm.bin.hS[sv[k] >> 6], 1);
    }
    __syncthreads();
    if (t < BKT) { sm.bin.scD[t] = sm.bin.hD[t]; sm.bin.bD[t] = atomicAdd(cnt + (2 * g + 0) * BKT + t, sm.bin.hD[t]); }
    else if (t < 2 * BKT) { int i = t - BKT; sm.bin.scS[i] = sm.bin.hS[i]; sm.bin.bS[i] = atomicAdd(cnt + (2 * g + 1) * BKT + i, sm.bin.hS[i]); }
    __syncthreads();
    for (int o = 1; o < BKT; o <<= 1) {   // Hillis-Steele inclusive scans
      int v = 0;
      if (t < BKT) { if (t >= o) v = sm.bin.scD[t - o]; }
      else if (t < 2 * BKT) { int i = t - BKT; if (i >= o) v = sm.bin.scS[i - o]; }
      __syncthreads();
      if (t < BKT) sm.bin.scD[t] += v;
      else if (t < 2 * BKT) sm.bin.scS[t - BKT] += v;
      __syncthreads();
    }
#pragma unroll
    for (int k = 0; k < 4; ++k) {
      int kb = dv[k] >> 6;
      int pos = (sm.bin.scD[kb] - sm.bin.hD[kb]) + atomicAdd(&sm.bin.cD[kb], 1);
      sm.bin.ldsD[pos] = (sv[k] << 6) | (dv[k] & 63);
      sm.bin.kbAD[pos] = (unsigned char)kb;
      kb = sv[k] >> 6;
      pos = (sm.bin.scS[kb] - sm.bin.hS[kb]) + atomicAdd(&sm.bin.cS[kb], 1);
      sm.bin.ldsS[pos] = (dv[k] << 6) | (sv[k] & 63);
      sm.bin.kbAS[pos] = (unsigned char)kb;
    }
    __syncthreads();
    int* bdg = binD + (size_t)g * BKT * CAP;
    int* bsg = binS + (size_t)g * BKT * CAP;
#pragma unroll
    for (int k = 0; k < 4; ++k) {
      int i = t + k * 512;
      int kb = sm.bin.kbAD[i];
      bdg[kb * CAP + sm.bin.bD[kb] + (i - (sm.bin.scD[kb] - sm.bin.hD[kb]))] = sm.bin.ldsD[i];
      kb = sm.bin.kbAS[i];
      bsg[kb * CAP + sm.bin.bS[kb] + (i - (sm.bin.scS[kb] - sm.bin.hS[kb]))] = sm.bin.ldsS[i];
    }
    // u: blocks 0..31, threads 0..127 (independent of bin LDS)
    if (blockIdx.x < 32 && t < 128) {
      int g2 = blockIdx.x >> 4, sd = (blockIdx.x >> 3) & 1, head = blockIdx.x & 7;
      const float* W = g2 ? W2 : W1;
      const float* att = g2 ? (sd ? ad2 : as2) : (sd ? ad1 : as1);
      const float* wr2 = W + (size_t)t * 1024 + head * 128;
      const float* ar = att + head * 128;
      float s = 0.f;
#pragma unroll 8
      for (int c = 0; c < 128; ++c) s += wr2[c] * ar[c];
      uu[g2 * 2048 + sd * 1024 + head * 128 + t] = s;
    }
  }
  gbar(bar, GRID * 1);

  // ---------- P1: a_src/a_dst = x . u ----------
  {
    int unit = blockIdx.x, g = unit >> 7, tile = unit & 127;
    const float* x = g ? x2 : x1;
    const float* ug = uu + g * 2048;
    for (int i = t; i < 2048; i += 512) sm.a.us[i >> 7][i & 127] = ug[i];
    int n0 = tile * 64;
    const float* xb = x + (size_t)n0 * 128;
    for (int i = t; i < 64 * 128; i += 512) sm.a.xs[i >> 7][i & 127] = xb[i];
    __syncthreads();
    int nl = t & 63, j0 = (t >> 6) * 2;
    float a0 = 0.f, a1 = 0.f;
#pragma unroll 4
    for (int k = 0; k < 128; ++k) {
      float xv = sm.a.xs[nl][k];
      a0 += xv * sm.a.us[j0][k];
      a1 += xv * sm.a.us[j0 + 1][k];
    }
    int n = n0 + nl;
    float* outp = (j0 < 8) ? (asrc + g * (NN * 8) + n * 8 + j0)
                           : (adst + g * (NN * 8) + n * 8 + (j0 - 8));
    outp[0] = a0; outp[1] = a1;
  }
  gbar(bar, GRID * 2);

  // ---------- P2: den per dst-bucket -> pr = (adst, 1/den) ----------
  {
    int unit = blockIdx.x, g = unit >> 7, b = unit & 127;
    int lo = b * RNG;
    const float* as_ = asrc + g * (NN * 8);
    const float* ad_ = adst + g * (NN * 8);
    float2* prg = (float2*)pr + (size_t)g * (NN * 8);
    for (int i = t; i < RNG * 8; i += 512) {
      float avv = ad_[lo * 8 + i];
      float v = as_[lo * 8 + i] + avv;     // self loop (s == d)
      v = v > 0.f ? v : NEG * v;
      sm.dr.adsts[i] = avv;
      sm.dr.den[i] = __expf(v);
    }
    __syncthreads();
    int n = cnt[(2 * g + 0) * BKT + b];
    const int* recs = binD + (size_t)g * BKT * CAP + b * CAP;
    int rid = t >> 3, h = t & 7;
    for (int base = 0; base < n; base += 256) {
      int rv[4]; bool ok[4]; float svv[4];
#pragma unroll
      for (int k = 0; k < 4; ++k) {
        int i = base + k * 64 + rid;
        ok[k] = i < n;
        rv[k] = ok[k] ? recs[i] : 0;
      }
#pragma unroll
      for (int k = 0; k < 4; ++k) svv[k] = ok[k] ? as_[(rv[k] >> 6) * 8 + h] : 0.f;
#pragma unroll
      for (int k = 0; k < 4; ++k) {
        if (ok[k]) {
          int dl = rv[k] & 63;
          float v = svv[k] + sm.dr.adsts[dl * 8 + h];
          v = v > 0.f ? v : NEG * v;
          atomicAdd(&sm.dr.den[dl * 8 + h], __expf(v));
        }
      }
    }
    __syncthreads();
    for (int i = t; i < RNG * 8; i += 512)
      prg[lo * 8 + i] = make_float2(sm.dr.adsts[i], 1.0f / sm.dr.den[i]);
  }
  gbar(bar, GRID * 3);

  // ---------- P3: wacc per src-bucket ----------
  {
    int unit = blockIdx.x, g = unit >> 7, b = unit & 127;
    int lo = b * RNG;
    const float* as_ = asrc + g * (NN * 8);
    const float2* prg = (const float2*)pr + (size_t)g * (NN * 8);
    for (int i = t; i < RNG * 8; i += 512) {
      float sva = as_[lo * 8 + i];
      float2 f2 = prg[lo * 8 + i];
      float v = sva + f2.x;                // self loop
      v = v > 0.f ? v : NEG * v;
      sm.wr.asrcs[i] = sva;
      sm.wr.wv[i] = __expf(v) * f2.y;
    }
    __syncthreads();
    int n = cnt[(2 * g + 1) * BKT + b];
    const int* recs = binS + (size_t)g * BKT * CAP + b * CAP;
    int rid = t >> 3, h = t & 7;
    for (int base = 0; base < n; base += 256) {
      int rv[4]; bool ok[4]; float2 pv[4];
#pragma unroll
      for (int k = 0; k < 4; ++k) {
        int i = base + k * 64 + rid;
        ok[k] = i < n;
        rv[k] = ok[k] ? recs[i] : 0;
      }
#pragma unroll
      for (int k = 0; k < 4; ++k)
        pv[k] = ok[k] ? prg[(size_t)(rv[k] >> 6) * 8 + h] : make_float2(0.f, 0.f);
#pragma unroll
      for (int k = 0; k < 4; ++k) {
        if (ok[k]) {
          int sl = rv[k] & 63;
          float v = sm.wr.asrcs[sl * 8 + h] + pv[k].x;
          v = v > 0.f ? v : NEG * v;
          atomicAdd(&sm.wr.wv[sl * 8 + h], __expf(v) * pv[k].y);
        }
      }
    }
    __syncthreads();
    for (int i = t; i < RNG * 8; i += 512)
      wacc[g * (NN * 8) + lo * 8 + i] = sm.wr.wv[i];
  }
  gbar(bar, GRID * 4);

  // ---------- P4: g partials (atomic-free) ----------
  {
    int unit = blockIdx.x, g = unit >> 7, chunk = unit & 127;
    int n0 = chunk * 64;
    const float* x = g ? x2 : x1;
    const float* w = wacc + g * (NN * 8);
    int k = t & 127, h0 = (t >> 7) * 2;
    float a0 = 0.f, a1 = 0.f;
#pragma unroll 4
    for (int n = n0; n < n0 + 64; ++n) {
      float xv = x[(size_t)n * 128 + k];
      float2 w2 = *(const float2*)(w + (size_t)n * 8 + h0);
      a0 += xv * w2.x; a1 += xv * w2.y;
    }
    float* gp = gpart + (size_t)unit * 1024;
    gp[h0 * 128 + k] = a0;
    gp[(h0 + 1) * 128 + k] = a1;
  }
  gbar(bar, GRID * 5);

  // ---------- P5: reduce partials -> g ----------
  {
    int e0 = blockIdx.x * 8;
    int g = e0 >> 10, idx = e0 & 1023;
    const float* gp = gpart + (size_t)(g * 128) * 1024;
    int c = t >> 3, eoff = t & 7;
    float v = gp[(size_t)c * 1024 + idx + eoff] + gp[(size_t)(c + 64) * 1024 + idx + eoff];
    sm.red[t] = v;
    __syncthreads();
    for (int cs = 32; cs >= 1; cs >>= 1) {
      if (t < cs * 8) sm.red[t] += sm.red[t + cs * 8];
      __syncthreads();
    }
    if (t < 8) gg[e0 + t] = sm.red[t];
  }
  gbar(bar, GRID * 6);

  // ---------- P6: memb = g @ W / N + b ----------
  {
    int e0 = blockIdx.x * 8;
    int g = e0 >> 10, e1024 = e0 & 1023, head = e1024 >> 7;
    const float* W = g ? W2 : W1;
    const float* bb = g ? b2 : b1;
    const float* gr = gg + g * 1024 + head * 128;
    int k2 = t >> 3, eoff = t & 7;
    float v = gr[k2] * W[(size_t)k2 * 1024 + e1024 + eoff]
            + gr[k2 + 64] * W[(size_t)(k2 + 64) * 1024 + e1024 + eoff];
    sm.red[t] = v;
    __syncthreads();
    for (int cs = 32; cs >= 1; cs >>= 1) {
      if (t < cs * 8) sm.red[t] += sm.red[t + cs * 8];
      __syncthreads();
    }
    if (t < 8) memb[e0 + t] = sm.red[t] * (1.0f / (float)NN) + bb[e1024 + t];
  }
  gbar(bar, GRID * 7);

  // ---------- P7: out = [memb(g1); memb(g0)] @ Wl + bl ----------
  {
    int b = blockIdx.x, j = b & 127;
    const float* m = (b < 128) ? (memb + 1024) : memb;
    float v = m[t] * Wl[(size_t)t * 128 + j] + m[t + 512] * Wl[(size_t)(t + 512) * 128 + j];
    sm.red[t] = v;
    __syncthreads();
    for (int s = 256; s >= 1; s >>= 1) {
      if (t < s) sm.red[t] += sm.red[t + s];
      __syncthreads();
    }
    if (t == 0) out[b] = sm.red[0] + bl[j];
  }
}

extern "C" void kernel_launch(void* const* d_in, const int* in_sizes, int n_in,
                              void* d_out, int out_size, void* d_ws, size_t ws_size,
                              hipStream_t stream) {
  const float* x1  = (const float*)d_in[0];
  const int*   ei1 = (const int*)d_in[1];
  const float* W1  = (const float*)d_in[2];
  const float* as1 = (const float*)d_in[3];
  const float* ad1 = (const float*)d_in[4];
  const float* b1  = (const float*)d_in[5];
  const float* x2  = (const float*)d_in[6];
  const int*   ei2 = (const int*)d_in[7];
  const float* W2  = (const float*)d_in[8];
  const float* as2 = (const float*)d_in[9];
  const float* ad2 = (const float*)d_in[10];
  const float* b2  = (const float*)d_in[11];
  const float* Wl  = (const float*)d_in[12];
  const float* bl  = (const float*)d_in[13];

  hipMemsetAsync(d_ws, 0, ZERO_BYTES, stream);   // bar + cnt

  k_mega<<<GRID, 512, 0, stream>>>(x1, ei1, W1, as1, ad1, b1,
                                   x2, ei2, W2, as2, ad2, b2,
                                   Wl, bl, (float*)d_out,
                                   (int*)d_ws, (float*)d_ws);
}